// Round 2
// baseline (25593.707 us; speedup 1.0000x reference)
//
#include <hip/hip_runtime.h>
#include <hip/hip_bf16.h>
#include <math.h>

// Problem constants (from reference)
#define L   8
#define H   1024
#define NH  16
#define KVH 8
#define HD  128
#define FF  3072
#define V   32000
#define MAXSEQ 2048
#define S   1024
#define EPS 1e-6f
#define G   (NH / KVH)   // 2

// ---------------- embed: hidden[s][h] = u8[id][h]*scale[id] + zp[id] ----------------
// NOTE: harness delivers ALL integer inputs as int32 (contract: "integer -> const int*"),
// including the uint8 embed table. Round-1 bug was reading it as bytes.
__global__ __launch_bounds__(256) void embed_kernel(const int* __restrict__ ids,
                                                    const int* __restrict__ ed,
                                                    const float* __restrict__ scale,
                                                    const float* __restrict__ zp,
                                                    float* __restrict__ hidden)
{
    const int s = blockIdx.x;
    const int id = ids[s];
    const float sc = scale[id];
    const float z  = zp[id];
    const int* row = ed + (size_t)id * H;
    float* out = hidden + (size_t)s * H;
    for (int h = threadIdx.x; h < H; h += 256)
        out[h] = (float)row[h] * sc + z;
}

// ---------------- RMSNorm over H=1024 columns, one block per row ----------------
__global__ __launch_bounds__(256) void rmsnorm_kernel(const float* __restrict__ x,
                                                      const float* __restrict__ w,
                                                      float* __restrict__ out)
{
    const int row = blockIdx.x;
    const float* xp = x + (size_t)row * H;
    float s = 0.f;
    for (int c = threadIdx.x; c < H; c += 256) { float v = xp[c]; s += v * v; }
    __shared__ float red[256];
    red[threadIdx.x] = s; __syncthreads();
    for (int st = 128; st > 0; st >>= 1) {
        if (threadIdx.x < st) red[threadIdx.x] += red[threadIdx.x + st];
        __syncthreads();
    }
    const float inv = 1.0f / sqrtf(red[0] / (float)H + EPS);
    float* op = out + (size_t)row * H;
    for (int c = threadIdx.x; c < H; c += 256)
        op[c] = w[c] * (xp[c] * inv);
}

// ---------------- fp32 tiled GEMM: C[M,N] = A[M,K] @ B[K,N]  (optionally +=) -------
// M,N multiples of 64; K multiple of 16. Row-major everything.
#define BM 64
#define BN 64
#define BK 16
__global__ __launch_bounds__(256) void gemm_kernel(const float* __restrict__ A,
                                                   const float* __restrict__ B,
                                                   float* __restrict__ C,
                                                   int M, int N, int K, int addC)
{
    __shared__ float As[BK][BM + 1];
    __shared__ __align__(16) float Bs[BK][BN];
    const int tid = threadIdx.x;
    const int tx = tid & 15, ty = tid >> 4;
    const int arow = tid >> 2, acol = (tid & 3) * 4;
    const int brow = tid >> 4, bcol = (tid & 15) * 4;
    const float* Ab = A + (size_t)(blockIdx.y * BM) * K;
    const float* Bb = B + blockIdx.x * BN;
    float acc[4][4] = {};
    for (int k0 = 0; k0 < K; k0 += BK) {
        float4 av = *(const float4*)(Ab + (size_t)arow * K + k0 + acol);
        As[acol + 0][arow] = av.x; As[acol + 1][arow] = av.y;
        As[acol + 2][arow] = av.z; As[acol + 3][arow] = av.w;
        *(float4*)(&Bs[brow][bcol]) = *(const float4*)(Bb + (size_t)(k0 + brow) * N + bcol);
        __syncthreads();
#pragma unroll
        for (int k = 0; k < BK; k++) {
            float a[4], b[4];
#pragma unroll
            for (int r = 0; r < 4; r++) a[r] = As[k][ty * 4 + r];
#pragma unroll
            for (int c = 0; c < 4; c++) b[c] = Bs[k][tx * 4 + c];
#pragma unroll
            for (int r = 0; r < 4; r++)
#pragma unroll
                for (int c = 0; c < 4; c++)
                    acc[r][c] += a[r] * b[c];
        }
        __syncthreads();
    }
    float* Cb = C + (size_t)(blockIdx.y * BM + ty * 4) * N + blockIdx.x * BN + tx * 4;
    for (int r = 0; r < 4; r++) {
        float* cp = Cb + (size_t)r * N;
        if (addC) {
            cp[0] += acc[r][0]; cp[1] += acc[r][1]; cp[2] += acc[r][2]; cp[3] += acc[r][3];
        } else {
            cp[0] = acc[r][0]; cp[1] = acc[r][1]; cp[2] = acc[r][2]; cp[3] = acc[r][3];
        }
    }
}

// ------- fused per-(s,head) RMSNorm (over HD) + RoPE, in place. nheads = NH or KVH ----
__global__ __launch_bounds__(128) void qknorm_rope_kernel(float* __restrict__ x,
                                                          const float* __restrict__ nw,
                                                          const float* __restrict__ cose,
                                                          const float* __restrict__ sine,
                                                          int nheads)
{
    const int row = blockIdx.x;          // s*nheads + head
    const int s = row / nheads;
    const int d = threadIdx.x;           // 0..127
    float* xp = x + (size_t)row * HD;
    const float v = xp[d];
    __shared__ float red[128];
    red[d] = v * v; __syncthreads();
    for (int st = 64; st > 0; st >>= 1) {
        if (d < st) red[d] += red[d + st];
        __syncthreads();
    }
    const float inv = 1.0f / sqrtf(red[0] / (float)HD + EPS);
    const float xn = nw[d] * (v * inv);
    __shared__ float xs[128];
    xs[d] = xn; __syncthreads();
    const float rot = (d < 64) ? -xs[d + 64] : xs[d - 64];
    const float c  = cose[(size_t)s * HD + d];
    const float sn = sine[(size_t)s * HD + d];
    xp[d] = xn * c + rot * sn;
}

// ---------------- fused causal attention: one block per (head, q-row) ----------------
// q: (S, NH, HD), k,v: (S, KVH, HD), ao: (S, NH, HD)
__global__ __launch_bounds__(256) void attn_kernel(const float* __restrict__ q,
                                                   const float* __restrict__ k,
                                                   const float* __restrict__ v,
                                                   float* __restrict__ ao)
{
    const int h = blockIdx.x;    // 0..NH-1
    const int sq = blockIdx.y;   // 0..S-1
    const int kvh = h >> 1;      // G = 2
    const int tid = threadIdx.x;
    __shared__ __align__(16) float qs[HD];
    __shared__ float sc[S];
    __shared__ float red[256];
    __shared__ float gmaxs, gsums;
    if (tid < HD) qs[tid] = q[((size_t)sq * NH + h) * HD + tid];
    __syncthreads();
    const int n = sq + 1;        // masked keys (sk>sq) underflow to 0 in fp32 exp — skip them
    for (int sk = tid; sk < n; sk += 256) {
        const float4* kp = (const float4*)(k + ((size_t)sk * KVH + kvh) * HD);
        float acc = 0.f;
#pragma unroll
        for (int d4 = 0; d4 < HD / 4; d4++) {
            float4 kv = kp[d4];
            float4 qv = *(const float4*)(qs + d4 * 4);
            acc += qv.x * kv.x + qv.y * kv.y + qv.z * kv.z + qv.w * kv.w;
        }
        sc[sk] = acc;
    }
    __syncthreads();
    // max
    float m = -3.0e38f;
    for (int sk = tid; sk < n; sk += 256) m = fmaxf(m, sc[sk]);
    red[tid] = m; __syncthreads();
    for (int st = 128; st > 0; st >>= 1) {
        if (tid < st) red[tid] = fmaxf(red[tid], red[tid + st]);
        __syncthreads();
    }
    if (tid == 0) gmaxs = red[0];
    __syncthreads();
    const float gmax = gmaxs;
    float lsum = 0.f;
    for (int sk = tid; sk < n; sk += 256) {
        float p = expf(sc[sk] - gmax);
        sc[sk] = p;
        lsum += p;
    }
    __syncthreads();   // all sc writes done before PV reads
    red[tid] = lsum; __syncthreads();
    for (int st = 128; st > 0; st >>= 1) {
        if (tid < st) red[tid] += red[tid + st];
        __syncthreads();
    }
    if (tid == 0) gsums = red[0];
    __syncthreads();
    const float inv = 1.0f / gsums;
    // PV: 2 partitions over sk, 128 dims each
    const int d = tid & 127, half = tid >> 7;
    float acc = 0.f;
    for (int sk = half; sk < n; sk += 2)
        acc += sc[sk] * v[((size_t)sk * KVH + kvh) * HD + d];
    red[tid] = acc; __syncthreads();
    if (tid < 128)
        ao[((size_t)sq * NH + h) * HD + tid] = (red[tid] + red[tid + 128]) * inv;
}

// ---------------- silu(gate) * up, in place into gate ----------------
__global__ __launch_bounds__(256) void silumul_kernel(float* __restrict__ g,
                                                      const float* __restrict__ u, int n)
{
    const int i = blockIdx.x * 256 + threadIdx.x;
    if (i < n) {
        float x = g[i];
        g[i] = (x / (1.0f + expf(-x))) * u[i];
    }
}

// ---------------- logits: out[v] = h(1024) . W[:,v], W row-major (H, V) ----------------
__global__ __launch_bounds__(256) void logits_kernel(const float* __restrict__ h,
                                                     const float* __restrict__ W,
                                                     float* __restrict__ out)
{
    __shared__ float hs[H];
    for (int i = threadIdx.x; i < H; i += 256) hs[i] = h[i];
    __syncthreads();
    const int v = blockIdx.x * 256 + threadIdx.x;
    float acc = 0.f;
    for (int kk = 0; kk < H; kk++)
        acc += hs[kk] * W[(size_t)kk * V + v];
    out[v] = acc;
}

// ---------------- argmax over V, first-max tie-break ----------------
__global__ __launch_bounds__(1024) void argmax_kernel(const float* __restrict__ x,
                                                      int* __restrict__ out)
{
    const int tid = threadIdx.x;
    float best = -3.0e38f; int bi = V;
    for (int v = tid; v < V; v += 1024) {
        float val = x[v];
        if (val > best) { best = val; bi = v; }
    }
    __shared__ float bv[1024];
    __shared__ int bidx[1024];
    bv[tid] = best; bidx[tid] = bi; __syncthreads();
    for (int st = 512; st > 0; st >>= 1) {
        if (tid < st) {
            if (bv[tid + st] > bv[tid] ||
                (bv[tid + st] == bv[tid] && bidx[tid + st] < bidx[tid])) {
                bv[tid] = bv[tid + st]; bidx[tid] = bidx[tid + st];
            }
        }
        __syncthreads();
    }
    if (tid == 0) out[0] = bidx[0];
}

extern "C" void kernel_launch(void* const* d_in, const int* in_sizes, int n_in,
                              void* d_out, int out_size, void* d_ws, size_t ws_size,
                              hipStream_t stream)
{
    // inputs per setup_inputs() order
    const int*   input_ids    = (const int*)d_in[2];
    const int*   embed_data   = (const int*)d_in[5];   // uint8 table, delivered as int32
    const float* zero_point   = (const float*)d_in[6];
    const float* scale        = (const float*)d_in[7];
    const float* cos_emb      = (const float*)d_in[8]; // (1, MAX, HD); past_len = 0
    const float* sin_emb      = (const float*)d_in[9];
    const float* ln1_w        = (const float*)d_in[10];
    const float* q_w          = (const float*)d_in[11];
    const float* k_w          = (const float*)d_in[12];
    const float* v_w          = (const float*)d_in[13];
    const float* q_norm_w     = (const float*)d_in[14];
    const float* k_norm_w     = (const float*)d_in[15];
    const float* o_w          = (const float*)d_in[16];
    const float* ln2_w        = (const float*)d_in[17];
    const float* gate_w       = (const float*)d_in[18];
    const float* up_w         = (const float*)d_in[19];
    const float* down_w       = (const float*)d_in[20];
    const float* final_norm_w = (const float*)d_in[21];
    const float* lm_head_w    = (const float*)d_in[22];

    // workspace layout (floats); ~34 MB total.
    // attention buffers (q/k/v/ao) and MLP buffers (gate/up) are live in disjoint
    // phases -> alias them over one 6M-float region.
    const size_t M1 = 1024 * 1024;
    float* ws     = (float*)d_ws;
    float* hidden = ws;              // 1M floats
    float* hn     = ws + M1;         // 1M
    float* big    = ws + 2 * M1;     // 6M shared region
    float* qbuf   = big;             // 2M   (S*NH*HD)
    float* kbuf   = big + 2 * M1;    // 1M   (S*KVH*HD)
    float* vbuf   = big + 3 * M1;    // 1M
    float* aobuf  = big + 4 * M1;    // 2M
    float* gbuf   = big;             // 3M   (S*FF) aliases q+k
    float* ubuf   = big + 3 * M1;    // 3M   aliases v+ao
    float* lbuf   = ws + 8 * M1;     // V floats

    embed_kernel<<<S, 256, 0, stream>>>(input_ids, embed_data, scale, zero_point, hidden);

    for (int i = 0; i < L; i++) {
        rmsnorm_kernel<<<S, 256, 0, stream>>>(hidden, ln1_w + (size_t)i * H, hn);

        gemm_kernel<<<dim3((NH * HD) / BN, S / BM), 256, 0, stream>>>(
            hn, q_w + (size_t)i * H * NH * HD, qbuf, S, NH * HD, H, 0);
        gemm_kernel<<<dim3((KVH * HD) / BN, S / BM), 256, 0, stream>>>(
            hn, k_w + (size_t)i * H * KVH * HD, kbuf, S, KVH * HD, H, 0);
        gemm_kernel<<<dim3((KVH * HD) / BN, S / BM), 256, 0, stream>>>(
            hn, v_w + (size_t)i * H * KVH * HD, vbuf, S, KVH * HD, H, 0);

        qknorm_rope_kernel<<<S * NH, 128, 0, stream>>>(
            qbuf, q_norm_w + (size_t)i * HD, cos_emb, sin_emb, NH);
        qknorm_rope_kernel<<<S * KVH, 128, 0, stream>>>(
            kbuf, k_norm_w + (size_t)i * HD, cos_emb, sin_emb, KVH);

        attn_kernel<<<dim3(NH, S), 256, 0, stream>>>(qbuf, kbuf, vbuf, aobuf);

        gemm_kernel<<<dim3(H / BN, S / BM), 256, 0, stream>>>(
            aobuf, o_w + (size_t)i * NH * HD * H, hidden, S, H, NH * HD, 1);

        rmsnorm_kernel<<<S, 256, 0, stream>>>(hidden, ln2_w + (size_t)i * H, hn);

        gemm_kernel<<<dim3(FF / BN, S / BM), 256, 0, stream>>>(
            hn, gate_w + (size_t)i * H * FF, gbuf, S, FF, H, 0);
        gemm_kernel<<<dim3(FF / BN, S / BM), 256, 0, stream>>>(
            hn, up_w + (size_t)i * H * FF, ubuf, S, FF, H, 0);

        silumul_kernel<<<(S * FF) / 256, 256, 0, stream>>>(gbuf, ubuf, S * FF);

        gemm_kernel<<<dim3(H / BN, S / BM), 256, 0, stream>>>(
            gbuf, down_w + (size_t)i * FF * H, hidden, S, H, FF, 1);
    }

    rmsnorm_kernel<<<1, 256, 0, stream>>>(hidden + (size_t)(S - 1) * H, final_norm_w, hn);
    logits_kernel<<<V / 256, 256, 0, stream>>>(hn, lm_head_w, lbuf);
    argmax_kernel<<<1, 1024, 0, stream>>>(lbuf, (int*)d_out);
}